// Round 14
// baseline (244718.970 us; speedup 1.0000x reference)
//
#include <hip/hip_runtime.h>
#include <math.h>

// ControlledNODE: sequential RK4 scan, T=65536 steps.
// Round-14: r12's validated TWO-barrier region structure (r13 proved the
// one-barrier merge races intermittently), with the pdrift LDS round-trip
// deleted:
//  * L3 is FULL-K per wave (r13's idea): each lane writes z2 for units
//    (lam, lam+64) -> every wave holds a complete z2 copy (x4-identical
//    replication, same validated pattern as xbuf); lane (m, sub) covers
//    units [sub*64,+64) with w3p[32]; one shfl_xor(32) -> full drift
//    wave-locally. pdrift write/read + its latency are gone.
//  * BARRIER-B retained purely as the skew limiter (carries no data) so
//    the inter-barrier regions are exactly r12's -- the delta that
//    separates passing r12 from racing r13.
//  * pex: single float2[128] (component wk per unit); write pre-A, read
//    post-A, next write separated by B -> no parity buffer needed.
// Weights/lane: W1 40 + W2 64 + W3 64 = 168 floats (r12: 136 -> VGPR 96).

constexpr int T_STEPS = 65536;
constexpr int HD  = 32;   // state dim
constexpr int HID = 128;  // hidden dim

typedef float v2f __attribute__((ext_vector_type(2)));

__device__ __forceinline__ v2f fma2(v2f a, v2f b, v2f c) {
    return __builtin_elementwise_fma(a, b, c);   // -> v_pk_fma_f32
}

__device__ __forceinline__ float silu_f(float a) {
    // a * sigmoid(a); exp overflow -> inf -> a/inf = 0 (correct limit)
    return a / (1.0f + __expf(-a));
}

// Workgroup barrier without vmcnt drain.
__device__ __forceinline__ void wg_barrier() {
    asm volatile("s_waitcnt lgkmcnt(0)" ::: "memory");
    __builtin_amdgcn_s_barrier();
    asm volatile("" ::: "memory");
}

__global__ __launch_bounds__(256, 1)
void node_scan(const float* __restrict__ U,
               const float* __restrict__ h0,
               const float* __restrict__ W1, const float* __restrict__ b1,
               const float* __restrict__ W2, const float* __restrict__ b2,
               const float* __restrict__ W3, const float* __restrict__ b3,
               const float* __restrict__ Wd, const float* __restrict__ bd,
               const float* __restrict__ Wt, const float* __restrict__ bt,
               const float* __restrict__ Wc, const float* __restrict__ bc,
               float* __restrict__ out)
{
    const int tid = threadIdx.x;    // 0..255
    const int lam = tid & 63;       // lane within wave
    const int w   = tid >> 6;       // wave 0..3
    const int wk  = w & 1;          // z1 half produced == L2 K-half
    const int wo  = w >> 1;         // L2 output half
    const int j1  = lam + wk * 64;  // L1 output unit
    const int o   = lam + wo * 64;  // L2 output unit
    const int m   = lam & 31;       // state/drift index
    const int sub = lam >> 5;       // L3 sub-split within wave

    __shared__ __align__(16) float  xbuf[HD];     // RK-stage state input
    __shared__ __align__(16) float  z1buf[HID];   // unit order
    __shared__ __align__(16) float  z2buf[HID];   // unit order, x4-replicated
    __shared__ __align__(16) float2 pex2[HID];    // [unit]{.x=k<64,.y=k>=64}

    // ---- one-time: weights into registers as packed pairs ----
    v2f w1p[20];                                  // rows 0..31 = x, 32..39 = u
#pragma unroll
    for (int i = 0; i < 20; ++i) {
        w1p[i].x = W1[(2 * i) * HID + j1];
        w1p[i].y = W1[(2 * i + 1) * HID + j1];
    }
    const float b1r = b1[j1];

    // W2 column o over K-half [wk*64, wk*64+64)
    v2f w2p[32];
#pragma unroll
    for (int kp = 0; kp < 32; ++kp) {
        const int k = wk * 64 + 2 * kp;
        w2p[kp].x = W2[k * HID + o];
        w2p[kp].y = W2[(k + 1) * HID + o];
    }
    const float b2a = b2[lam], b2b = b2[lam + 64];

    // W3: drift[m] partial over z2 units [sub*64, sub*64+64)
    v2f w3p[32];
#pragma unroll
    for (int i = 0; i < 32; ++i) {
        const int u0 = sub * 64 + 2 * i;
        w3p[i].x = W3[u0 * HD + m];
        w3p[i].y = W3[(u0 + 1) * HD + m];
    }
    const float b3r = b3[m];

    // heads: wave0 -> d, wave1 -> t, wave2 -> c, wave3 idle
    const float whr = (w == 0) ? Wd[m] : (w == 1) ? Wt[m] : (w == 2) ? Wc[m] : 0.0f;
    const float bh  = (w == 0) ? bd[0] : (w == 1) ? bt[0] : (w == 2) ? bc[0] : 0.0f;

    float hm   = h0[m];    // replicated in all 256 lanes
    float xm   = hm;       // current stage input state x[m]
    float kacc = 0.0f;

    const float DT  = 5.0f / 60.0f;
    const float HDT = 0.5f * DT;
    const float W6  = DT / 6.0f;

    // u double-buffer (same addr all lanes -> broadcast, L2-cached)
    float4 ua = *(const float4*)(U);
    float4 ub = *(const float4*)(U + 4);

    xbuf[m] = xm;                    // all lanes, identical values: benign
    wg_barrier();

    for (int t = 0; t < T_STEPS; ++t) {
        // prefetch next step's u (no vmcnt drain at barriers -> in flight)
        const int tn = (t + 1 < T_STEPS) ? (t + 1) : t;
        const float4 na = *(const float4*)(U + tn * 8);
        const float4 nb = *(const float4*)(U + tn * 8 + 4);

        // ---- heads from current h (pre-update): one head per wave ----
        {
            float p = hm * whr;
            p += __shfl_xor(p, 16);
            p += __shfl_xor(p, 8);
            p += __shfl_xor(p, 4);
            p += __shfl_xor(p, 2);
            p += __shfl_xor(p, 1);
            if (lam == 0 && w < 3) out[w * T_STEPS + t] = p + bh;
        }

        // ---- u-projection: constant across the 4 RK stages, hoisted ----
        float upj;
        {
            v2f u0; u0.x = ua.x; u0.y = ua.y;
            v2f u1; u1.x = ua.z; u1.y = ua.w;
            v2f u2; u2.x = ub.x; u2.y = ub.y;
            v2f u3; u3.x = ub.z; u3.y = ub.w;
            v2f up = {b1r, 0.0f};
            up = fma2(u0, w1p[16], up);
            up = fma2(u1, w1p[17], up);
            up = fma2(u2, w1p[18], up);
            up = fma2(u3, w1p[19], up);
            upj = up.x + up.y;
        }

#pragma unroll
        for (int st = 0; st < 4; ++st) {
            // ---- L1: z1[j1] = silu([x,u] @ W1 + b1) (replicated x2) ----
            v2f a0 = {upj, 0.0f}, a1 = {0.0f, 0.0f};
            const float4* xv = (const float4*)xbuf;
#pragma unroll
            for (int i4 = 0; i4 < 8; ++i4) {
                const float4 v = xv[i4];            // broadcast read (own writes)
                v2f lo; lo.x = v.x; lo.y = v.y;
                v2f hi; hi.x = v.z; hi.y = v.w;
                a0 = fma2(lo, w1p[2 * i4],     a0);
                a1 = fma2(hi, w1p[2 * i4 + 1], a1);
            }
            const v2f as = a0 + a1;
            z1buf[j1] = silu_f(as.x + as.y);        // waves (0,2) half0, (1,3) half1
            __builtin_amdgcn_wave_barrier();         // own z1 half < own reads

            // ---- L2: output o over own K-half [wk*64, +64) ----
            v2f c0 = {0.0f, 0.0f}, c1 = {0.0f, 0.0f};
            const float4* z1v = (const float4*)(z1buf + wk * 64);
#pragma unroll
            for (int i4 = 0; i4 < 16; ++i4) {
                const float4 v = z1v[i4];           // broadcast read (own half)
                v2f lo; lo.x = v.x; lo.y = v.y;
                v2f hi; hi.x = v.z; hi.y = v.w;
                c0 = fma2(lo, w2p[2 * i4],     c0);
                c1 = fma2(hi, w2p[2 * i4 + 1], c1);
            }
            const v2f cs = c0 + c1;
            const float mine = cs.x + cs.y;         // K-half partial for unit o
            ((float*)&pex2[o])[wk] = mine;          // component wk, unit o
            wg_barrier();                            // BARRIER-A: pex exchange

            // ---- z2 for units (lam, lam+64), identical in every wave ----
            const float2 e0 = pex2[lam];
            const float2 e1 = pex2[lam + 64];
            const float z2A = silu_f(e0.x + e0.y + b2a);
            const float z2B = silu_f(e1.x + e1.y + b2b);
            z2buf[lam]      = z2A;                  // x4 replicated: benign
            z2buf[lam + 64] = z2B;
            __builtin_amdgcn_wave_barrier();         // own z2 writes < own reads

            // ---- L3 FULL-K per wave: lane (m,sub) over [sub*64, +64) ----
            v2f p0 = {0.0f, 0.0f}, p1 = {0.0f, 0.0f};
            v2f p2 = {0.0f, 0.0f}, p3 = {0.0f, 0.0f};
            const float4* z2v = (const float4*)(z2buf + sub * 64);
#pragma unroll
            for (int i4 = 0; i4 < 16; ++i4) {
                const float4 v = z2v[i4];           // 2 addr groups: free
                v2f lo; lo.x = v.x; lo.y = v.y;
                v2f hi; hi.x = v.z; hi.y = v.w;
                if (i4 & 1) {
                    p2 = fma2(lo, w3p[2 * i4],     p2);
                    p3 = fma2(hi, w3p[2 * i4 + 1], p3);
                } else {
                    p0 = fma2(lo, w3p[2 * i4],     p0);
                    p1 = fma2(hi, w3p[2 * i4 + 1], p1);
                }
            }
            const v2f ps = (p0 + p1) + (p2 + p3);
            float pr = ps.x + ps.y;
            pr += __shfl_xor(pr, 32);   // combine sub halves within wave
            const float drift = pr + b3r;
            wg_barrier();                            // BARRIER-B: skew limiter
                                                     // (restores r12 regions)

            // ---- RK combine: ALL lanes redundantly (drift replicated) ----
            const float k = 0.02f * drift - 0.1f * xm;
            if (st == 0)      { kacc = k;           xm = hm + HDT * k; }
            else if (st == 1) { kacc += 2.0f * k;   xm = hm + HDT * k; }
            else if (st == 2) { kacc += 2.0f * k;   xm = hm + DT  * k; }
            else {
                kacc += k;
                float hn = hm + W6 * kacc;
                if (!isfinite(hn)) hn = 0.0f;        // nan_to_num BEFORE tanh
                hn = tanhf(hn);
                hn = fminf(fmaxf(hn, -5.0f), 5.0f);  // fidelity no-op after tanh
                hm = hn; xm = hn;
            }
            xbuf[m] = xm;   // all lanes, identical values: benign race
            __builtin_amdgcn_wave_barrier();         // wave-local: xbuf -> L1
        }
        ua = na; ub = nb;
    }

    if (tid < HD) out[3 * T_STEPS + tid] = hm;
}

extern "C" void kernel_launch(void* const* d_in, const int* in_sizes, int n_in,
                              void* d_out, int out_size, void* d_ws, size_t ws_size,
                              hipStream_t stream) {
    const float* U  = (const float*)d_in[0];
    const float* h0 = (const float*)d_in[1];
    const float* W1 = (const float*)d_in[2];
    const float* b1 = (const float*)d_in[3];
    const float* W2 = (const float*)d_in[4];
    const float* b2 = (const float*)d_in[5];
    const float* W3 = (const float*)d_in[6];
    const float* b3 = (const float*)d_in[7];
    const float* Wd = (const float*)d_in[8];
    const float* bd = (const float*)d_in[9];
    const float* Wt = (const float*)d_in[10];
    const float* bt = (const float*)d_in[11];
    const float* Wc = (const float*)d_in[12];
    const float* bc = (const float*)d_in[13];
    float* out = (float*)d_out;

    node_scan<<<1, 256, 0, stream>>>(U, h0, W1, b1, W2, b2, W3, b3,
                                     Wd, bd, Wt, bt, Wc, bc, out);
}